// Round 6
// baseline (158.062 us; speedup 1.0000x reference)
//
#include <hip/hip_runtime.h>

#define B_    1
#define N_    6
#define C_    80
#define D_    112
#define HF_   16
#define WF_   44
#define NX_   128
#define NY_   128
#define NZ_   1
#define HW_   (HF_ * WF_)          // 704
#define NPIX_ (NZ_ * NX_ * NY_)    // 16384
#define CAMHW_ (N_ * HW_)          // 4224
#define EMAIN_ 128                 // per-hw main entry slots (pow2; >= 112 same-case max)
#define EOV_   544                 // per-hw overflow slots (672 generic worst - 128)

// ---------------- 3x3 inverse (adjugate) ----------------
__device__ __forceinline__ void inv3(const float* m, float* o) {
    float a = m[0], b = m[1], c = m[2];
    float d = m[3], e = m[4], f = m[5];
    float g = m[6], h = m[7], i = m[8];
    float A  =  (e * i - f * h);
    float Bc = -(d * i - f * g);
    float Cc =  (d * h - e * g);
    float det = a * A + b * Bc + c * Cc;
    float id = 1.0f / det;
    o[0] = A * id;                  o[1] = -(b * i - c * h) * id;   o[2] =  (b * f - c * e) * id;
    o[3] = Bc * id;                 o[4] =  (a * i - c * g) * id;   o[5] = -(a * f - c * d) * id;
    o[6] = Cc * id;                 o[7] = -(a * h - b * g) * id;   o[8] =  (a * e - b * d) * id;
}

__device__ __forceinline__ int voxel_of(float xs, float ys, float dv, const float* sm) {
    const float* ip  = sm;       // invPost
    const float* cmb = sm + 9;   // rots @ inv(intrins)
    float ptx = sm[18], pty = sm[19], ptz = sm[20];
    float trx = sm[21], trY = sm[22], trz = sm[23];
    float p0x = xs - ptx, p0y = ys - pty, p0z = dv - ptz;
    float p1x = ip[0]*p0x + ip[1]*p0y + ip[2]*p0z;
    float p1y = ip[3]*p0x + ip[4]*p0y + ip[5]*p0z;
    float p1z = ip[6]*p0x + ip[7]*p0y + ip[8]*p0z;
    float qx = p1x * p1z, qy = p1y * p1z, qz = p1z;
    float rx = cmb[0]*qx + cmb[1]*qy + cmb[2]*qz + trx;
    float ry = cmb[3]*qx + cmb[4]*qy + cmb[5]*qz + trY;
    float rz = cmb[6]*qx + cmb[7]*qy + cmb[8]*qz + trz;
    const float lox = -50.8f - 0.4f;   // bx - dx/2, f32 fold matches np
    const float loy = -50.8f - 0.4f;
    const float loz = -10.0f;
    int ix = (int)((rx - lox) / 0.8f);   // trunc toward zero == astype(int32)
    int iy = (int)((ry - loy) / 0.8f);
    int iz = (int)((rz - loz) / 20.0f);
    bool val = (ix >= 0) && (ix < NX_) && (iy >= 0) && (iy < NY_) && (iz >= 0) && (iz < NZ_);
    return val ? ((iz * NX_ + ix) * NY_ + iy) : -1;
}

// entry = 2x int4: {vox, hw, w0, w1}, {w2, w3, w4, w5}  (weights as float bits)

// ===== K1: per-(h,w) softmax + geometry + run-merge + cam-combine emit =====
__global__ __launch_bounds__(256) void runs_kernel(
    const float* __restrict__ rots, const float* __restrict__ trans,
    const float* __restrict__ intrins, const float* __restrict__ post_rots,
    const float* __restrict__ post_trans,
    const float* __restrict__ depth_digit,
    int4* __restrict__ emain, int4* __restrict__ eov,
    int* __restrict__ cnt, int* __restrict__ ovcnt)
{
    const int hw = blockIdx.x;
    const int w  = hw % WF_;
    const int h  = hw / WF_;
    const int tid  = threadIdx.x;
    const int lane = tid & 63;
    const int wave = tid >> 6;

    __shared__ float s_prob[N_][D_];
    __shared__ short s_vox[N_][D_];
    __shared__ short s_runv[N_][D_];
    __shared__ float s_runw[N_][D_];
    __shared__ float s_mat[N_][24];
    __shared__ int   s_cnt[N_];
    __shared__ int   s_pref[N_ + 1];
    __shared__ int   s_same;

    for (int i = tid; i < N_ * D_; i += 256) {
        int cam = i / D_, d = i - cam * D_;
        s_prob[cam][d] = depth_digit[((size_t)cam * D_ + d) * HW_ + hw];
    }
    if (tid < N_) {
        float ipv[9], ii[9];
        inv3(post_rots + tid * 9, ipv);
        inv3(intrins + tid * 9, ii);
        const float* ro = rots + tid * 9;
        #pragma unroll
        for (int k = 0; k < 9; ++k) s_mat[tid][k] = ipv[k];
        #pragma unroll
        for (int r = 0; r < 3; ++r)
            #pragma unroll
            for (int c = 0; c < 3; ++c)
                s_mat[tid][9 + r * 3 + c] = ro[r*3+0]*ii[0*3+c] + ro[r*3+1]*ii[1*3+c] + ro[r*3+2]*ii[2*3+c];
        #pragma unroll
        for (int k = 0; k < 3; ++k) { s_mat[tid][18+k] = post_trans[tid*3+k]; s_mat[tid][21+k] = trans[tid*3+k]; }
    }
    __syncthreads();

    // softmax per camera (wave per camera; lanes 0..55 hold 2 bins)
    for (int cc = wave; cc < N_; cc += 4) {
        bool act = lane < 56;
        float l0 = act ? s_prob[cc][lane]      : -INFINITY;
        float l1 = act ? s_prob[cc][lane + 56] : -INFINITY;
        float m = fmaxf(l0, l1);
        #pragma unroll
        for (int o = 32; o > 0; o >>= 1) m = fmaxf(m, __shfl_xor(m, o));
        float e0 = act ? __expf(l0 - m) : 0.0f;
        float e1 = act ? __expf(l1 - m) : 0.0f;
        float s = e0 + e1;
        #pragma unroll
        for (int o = 32; o > 0; o >>= 1) s += __shfl_xor(s, o);
        float inv = 1.0f / s;
        if (act) { s_prob[cc][lane] = e0 * inv; s_prob[cc][lane + 56] = e1 * inv; }
    }

    // geometry
    {
        float xs = (float)((double)w * (703.0 / 43.0));  // np.linspace(0,703,44)
        float ys = (float)h * 17.0f;                     // np.linspace(0,255,16)
        for (int i = tid; i < N_ * D_; i += 256) {
            int cam = i / D_, d = i - cam * D_;
            float dval = 2.0f + 0.5f * (float)d;
            s_vox[cam][d] = (short)voxel_of(xs, ys, dval, s_mat[cam]);
        }
    }
    __syncthreads();

    // run-length merge per camera (6 threads)
    if (tid < N_) {
        int c2 = 0, last = -1;
        float wsum = 0.0f;
        for (int d = 0; d < D_; ++d) {
            int v = s_vox[tid][d];
            if (v < 0) continue;
            if (v == last) { wsum += s_prob[tid][d]; }
            else {
                if (last >= 0) { s_runv[tid][c2] = (short)last; s_runw[tid][c2] = wsum; ++c2; }
                last = v; wsum = s_prob[tid][d];
            }
        }
        if (last >= 0) { s_runv[tid][c2] = (short)last; s_runw[tid][c2] = wsum; ++c2; }
        s_cnt[tid] = c2;
    }
    __syncthreads();

    // cam run-structure equality + prefix
    if (tid == 0) {
        int same = 1, c0 = s_cnt[0];
        #pragma unroll
        for (int cam = 1; cam < N_; ++cam) same &= (s_cnt[cam] == c0);
        if (same) {
            for (int r = 0; r < c0 && same; ++r) {
                short v0 = s_runv[0][r];
                #pragma unroll
                for (int cam = 1; cam < N_; ++cam) same &= (s_runv[cam][r] == v0);
            }
        }
        s_same = same;
        int acc = 0;
        #pragma unroll
        for (int cam = 0; cam < N_; ++cam) { s_pref[cam] = acc; acc += s_cnt[cam]; }
        s_pref[N_] = acc;
    }
    __syncthreads();

    if (s_same) {
        int c0 = s_cnt[0];
        for (int r = tid; r < c0; r += 256) {
            size_t base = ((size_t)hw * EMAIN_ + r) * 2;
            emain[base]     = make_int4((int)s_runv[0][r], hw,
                                        __float_as_int(s_runw[0][r]), __float_as_int(s_runw[1][r]));
            emain[base + 1] = make_int4(__float_as_int(s_runw[2][r]), __float_as_int(s_runw[3][r]),
                                        __float_as_int(s_runw[4][r]), __float_as_int(s_runw[5][r]));
        }
        if (tid == 0) { cnt[hw] = c0; ovcnt[hw] = 0; }
    } else {
        int tcnt = s_pref[N_];
        for (int k = tid; k < tcnt; k += 256) {
            int cam = 0;
            #pragma unroll
            for (int cc = 1; cc < N_; ++cc) if (k >= s_pref[cc]) cam = cc;
            int r = k - s_pref[cam];
            float wv[N_] = {0.f, 0.f, 0.f, 0.f, 0.f, 0.f};
            wv[cam] = s_runw[cam][r];
            size_t base = (k < EMAIN_)
                ? ((size_t)hw * EMAIN_ + k) * 2
                : (size_t)0;   // placeholder, replaced below
            int4 a = make_int4((int)s_runv[cam][r], hw, __float_as_int(wv[0]), __float_as_int(wv[1]));
            int4 b = make_int4(__float_as_int(wv[2]), __float_as_int(wv[3]),
                               __float_as_int(wv[4]), __float_as_int(wv[5]));
            if (k < EMAIN_) {
                emain[base] = a; emain[base + 1] = b;
            } else {
                size_t ob = ((size_t)hw * EOV_ + (k - EMAIN_)) * 2;
                eov[ob] = a; eov[ob + 1] = b;
            }
        }
        if (tid == 0) { cnt[hw] = min(tcnt, EMAIN_); ovcnt[hw] = max(0, tcnt - EMAIN_); }
    }
}

// ===== K2: channel-owner LDS BEV plane; zero atomics to global =====
__global__ __launch_bounds__(512) void accum2_kernel(
    const float* __restrict__ img_feat,
    const int4* __restrict__ emain, const int4* __restrict__ eov,
    const int* __restrict__ cnt, const int* __restrict__ ovcnt,
    float* __restrict__ outp)
{
    const int c   = blockIdx.x;
    const int tid = threadIdx.x;

    __shared__ float s_plane[NPIX_];   // 64 KB
    __shared__ float s_feat[CAMHW_];   // 16.5 KB
    __shared__ int   s_cnt[HW_];
    __shared__ int   s_ov[HW_];
    __shared__ int   s_totov;

    if (tid == 0) s_totov = 0;
    __syncthreads();

    float4* p4 = (float4*)s_plane;
    for (int i = tid; i < NPIX_ / 4; i += 512) p4[i] = make_float4(0.f, 0.f, 0.f, 0.f);
    for (int i = tid; i < CAMHW_; i += 512) {
        int cam = i / HW_, hw = i - cam * HW_;
        s_feat[i] = img_feat[((size_t)cam * C_ + c) * HW_ + hw];
    }
    for (int i = tid; i < HW_; i += 512) {
        s_cnt[i] = cnt[i];
        int o = ovcnt[i];
        s_ov[i] = o;
        if (o) atomicAdd(&s_totov, 1);
    }
    __syncthreads();

    // main entries: flat slot loop with cheap skip (EMAIN_ = 128 = pow2)
    for (int i = tid; i < HW_ * EMAIN_; i += 512) {
        int hw = i >> 7;
        int slot = i & (EMAIN_ - 1);
        if (slot < s_cnt[hw]) {
            int4 a = emain[(size_t)i * 2];
            int4 b = emain[(size_t)i * 2 + 1];
            int vox = a.x, hww = a.y;
            float val;
            val = __int_as_float(a.z) * s_feat[hww];
            val = fmaf(__int_as_float(a.w), s_feat[HW_     + hww], val);
            val = fmaf(__int_as_float(b.x), s_feat[HW_ * 2 + hww], val);
            val = fmaf(__int_as_float(b.y), s_feat[HW_ * 3 + hww], val);
            val = fmaf(__int_as_float(b.z), s_feat[HW_ * 4 + hww], val);
            val = fmaf(__int_as_float(b.w), s_feat[HW_ * 5 + hww], val);
            atomicAdd(&s_plane[vox], val);
        }
    }
    // overflow entries (generic-camera case only; usually s_totov == 0)
    if (s_totov) {
        for (int i = tid; i < HW_ * EOV_; i += 512) {
            int hw = i / EOV_;
            int slot = i - hw * EOV_;
            if (slot < s_ov[hw]) {
                int4 a = eov[(size_t)i * 2];
                int4 b = eov[(size_t)i * 2 + 1];
                int vox = a.x, hww = a.y;
                float val;
                val = __int_as_float(a.z) * s_feat[hww];
                val = fmaf(__int_as_float(a.w), s_feat[HW_     + hww], val);
                val = fmaf(__int_as_float(b.x), s_feat[HW_ * 2 + hww], val);
                val = fmaf(__int_as_float(b.y), s_feat[HW_ * 3 + hww], val);
                val = fmaf(__int_as_float(b.z), s_feat[HW_ * 4 + hww], val);
                val = fmaf(__int_as_float(b.w), s_feat[HW_ * 5 + hww], val);
                atomicAdd(&s_plane[vox], val);
            }
        }
    }
    __syncthreads();

    // flush full plane: plain coalesced stores (covers 0xAA poison; no memset needed)
    float4* o4 = (float4*)(outp + (size_t)c * NPIX_);
    for (int i = tid; i < NPIX_ / 4; i += 512) o4[i] = p4[i];
}

// ===================== fallback (round-4 proven) =====================
__global__ __launch_bounds__(256) void scatter_merged(
    const float* __restrict__ rots, const float* __restrict__ trans,
    const float* __restrict__ intrins, const float* __restrict__ post_rots,
    const float* __restrict__ post_trans,
    const float* __restrict__ img_feat, const float* __restrict__ depth_digit,
    float* __restrict__ outp)
{
    const int hw = blockIdx.x;
    const int w  = hw % WF_;
    const int h  = hw / WF_;
    const int tid  = threadIdx.x;
    const int lane = tid & 63;
    const int wave = tid >> 6;

    __shared__ float s_prob[N_][D_];
    __shared__ float s_feat[N_][C_];
    __shared__ short s_vox[N_][D_];
    __shared__ short s_runv[N_][D_];
    __shared__ float s_runw[N_][D_];
    __shared__ float s_mat[N_][24];
    __shared__ int   s_cnt[N_];
    __shared__ int   s_same;

    for (int i = tid; i < N_ * D_; i += 256) {
        int cam = i / D_, d = i - cam * D_;
        s_prob[cam][d] = depth_digit[((size_t)cam * D_ + d) * HW_ + hw];
    }
    for (int i = tid; i < N_ * C_; i += 256) {
        int cam = i / C_, cc = i - cam * C_;
        s_feat[cam][cc] = img_feat[((size_t)cam * C_ + cc) * HW_ + hw];
    }
    if (tid < N_) {
        float ipv[9], ii[9];
        inv3(post_rots + tid * 9, ipv);
        inv3(intrins + tid * 9, ii);
        const float* ro = rots + tid * 9;
        #pragma unroll
        for (int k = 0; k < 9; ++k) s_mat[tid][k] = ipv[k];
        #pragma unroll
        for (int r = 0; r < 3; ++r)
            #pragma unroll
            for (int c = 0; c < 3; ++c)
                s_mat[tid][9 + r * 3 + c] = ro[r*3+0]*ii[0*3+c] + ro[r*3+1]*ii[1*3+c] + ro[r*3+2]*ii[2*3+c];
        #pragma unroll
        for (int k = 0; k < 3; ++k) { s_mat[tid][18+k] = post_trans[tid*3+k]; s_mat[tid][21+k] = trans[tid*3+k]; }
    }
    __syncthreads();

    for (int cc = wave; cc < N_; cc += 4) {
        bool act = lane < 56;
        float l0 = act ? s_prob[cc][lane]      : -INFINITY;
        float l1 = act ? s_prob[cc][lane + 56] : -INFINITY;
        float m = fmaxf(l0, l1);
        #pragma unroll
        for (int o = 32; o > 0; o >>= 1) m = fmaxf(m, __shfl_xor(m, o));
        float e0 = act ? __expf(l0 - m) : 0.0f;
        float e1 = act ? __expf(l1 - m) : 0.0f;
        float s = e0 + e1;
        #pragma unroll
        for (int o = 32; o > 0; o >>= 1) s += __shfl_xor(s, o);
        float inv = 1.0f / s;
        if (act) { s_prob[cc][lane] = e0 * inv; s_prob[cc][lane + 56] = e1 * inv; }
    }
    {
        float xs = (float)((double)w * (703.0 / 43.0));
        float ys = (float)h * 17.0f;
        for (int i = tid; i < N_ * D_; i += 256) {
            int cam = i / D_, d = i - cam * D_;
            float dval = 2.0f + 0.5f * (float)d;
            s_vox[cam][d] = (short)voxel_of(xs, ys, dval, s_mat[cam]);
        }
    }
    __syncthreads();
    if (tid < N_) {
        int c2 = 0, last = -1;
        float wsum = 0.0f;
        for (int d = 0; d < D_; ++d) {
            int v = s_vox[tid][d];
            if (v < 0) continue;
            if (v == last) { wsum += s_prob[tid][d]; }
            else {
                if (last >= 0) { s_runv[tid][c2] = (short)last; s_runw[tid][c2] = wsum; ++c2; }
                last = v; wsum = s_prob[tid][d];
            }
        }
        if (last >= 0) { s_runv[tid][c2] = (short)last; s_runw[tid][c2] = wsum; ++c2; }
        s_cnt[tid] = c2;
    }
    __syncthreads();
    if (tid == 0) {
        int same = 1, c0 = s_cnt[0];
        #pragma unroll
        for (int cam = 1; cam < N_; ++cam) same &= (s_cnt[cam] == c0);
        if (same) {
            for (int r = 0; r < c0 && same; ++r) {
                short v0 = s_runv[0][r];
                #pragma unroll
                for (int cam = 1; cam < N_; ++cam) same &= (s_runv[cam][r] == v0);
            }
        }
        s_same = same;
    }
    __syncthreads();
    if (s_same) {
        int c0 = s_cnt[0];
        int total = c0 * C_;
        for (int k = tid; k < total; k += 256) {
            int r = k / C_;
            int c = k - r * C_;
            int v = s_runv[0][r];
            float val = 0.0f;
            #pragma unroll
            for (int cam = 0; cam < N_; ++cam)
                val = fmaf(s_runw[cam][r], s_feat[cam][c], val);
            atomicAdd(&outp[(size_t)c * NPIX_ + v], val);
        }
    } else {
        for (int cam = 0; cam < N_; ++cam) {
            int c0 = s_cnt[cam];
            int total = c0 * C_;
            for (int k = tid; k < total; k += 256) {
                int r = k / C_;
                int c = k - r * C_;
                int v = s_runv[cam][r];
                atomicAdd(&outp[(size_t)c * NPIX_ + v], s_runw[cam][r] * s_feat[cam][c]);
            }
        }
    }
}

extern "C" void kernel_launch(void* const* d_in, const int* in_sizes, int n_in,
                              void* d_out, int out_size, void* d_ws, size_t ws_size,
                              hipStream_t stream) {
    const float* rots        = (const float*)d_in[1];
    const float* trans       = (const float*)d_in[2];
    const float* intrins     = (const float*)d_in[3];
    const float* post_rots   = (const float*)d_in[4];
    const float* post_trans  = (const float*)d_in[5];
    const float* img_feat    = (const float*)d_in[6];
    const float* depth_digit = (const float*)d_in[7];
    float* outp = (float*)d_out;

    const size_t emain_b = (size_t)HW_ * EMAIN_ * 32;   // 2.88 MB
    const size_t eov_b   = (size_t)HW_ * EOV_ * 32;     // 12.25 MB
    const size_t cnt_b   = (size_t)HW_ * 4;
    const size_t ovcnt_b = (size_t)HW_ * 4;
    const size_t need = emain_b + eov_b + cnt_b + ovcnt_b;

    if (ws_size >= need) {
        char* p = (char*)d_ws;
        int4* emain = (int4*)p;  p += emain_b;
        int4* eov   = (int4*)p;  p += eov_b;
        int*  cnt   = (int*)p;   p += cnt_b;
        int*  ovcnt = (int*)p;

        runs_kernel<<<HW_, 256, 0, stream>>>(rots, trans, intrins, post_rots, post_trans,
                                             depth_digit, emain, eov, cnt, ovcnt);
        accum2_kernel<<<C_, 512, 0, stream>>>(img_feat, emain, eov, cnt, ovcnt, outp);
    } else {
        hipMemsetAsync(outp, 0, (size_t)out_size * sizeof(float), stream);
        scatter_merged<<<HW_, 256, 0, stream>>>(rots, trans, intrins, post_rots, post_trans,
                                                img_feat, depth_digit, outp);
    }
}

// Round 8
// 101.734 us; speedup vs baseline: 1.5537x; 1.5537x over previous
//
#include <hip/hip_runtime.h>
#include <limits.h>

#define N_    6
#define C_    80
#define D_    112
#define HF_   16
#define WF_   44
#define NX_   128
#define NY_   128
#define HW_   (HF_ * WF_)          // 704
#define NPIX_ (NX_ * NY_)          // 16384
#define TPX_  4                    // pixels per tile (consecutive w)
#define NTW_  (WF_ / TPX_)         // 11
#define NT_   (HF_ * NTW_)         // 176 blocks
#define PC_   (N_ * TPX_)          // 24 (px,cam) lists per tile
#define CAP_  256                  // max bbox slots (fast path)
#define WPAD_ 25                   // weight row stride (coprime w/ 32 banks)

// ---------------- 3x3 inverse (adjugate) ----------------
__device__ __forceinline__ void inv3(const float* m, float* o) {
    float a = m[0], b = m[1], c = m[2];
    float d = m[3], e = m[4], f = m[5];
    float g = m[6], h = m[7], i = m[8];
    float A  =  (e * i - f * h);
    float Bc = -(d * i - f * g);
    float Cc =  (d * h - e * g);
    float det = a * A + b * Bc + c * Cc;
    float id = 1.0f / det;
    o[0] = A * id;                  o[1] = -(b * i - c * h) * id;   o[2] =  (b * f - c * e) * id;
    o[3] = Bc * id;                 o[4] =  (a * i - c * g) * id;   o[5] = -(a * f - c * d) * id;
    o[6] = Cc * id;                 o[7] = -(a * h - b * g) * id;   o[8] =  (a * e - b * d) * id;
}

__device__ __forceinline__ int voxel_of(float xs, float ys, float dv, const float* sm) {
    const float* ip  = sm;       // invPost
    const float* cmb = sm + 9;   // rots @ inv(intrins)
    float ptx = sm[18], pty = sm[19], ptz = sm[20];
    float trx = sm[21], trY = sm[22], trz = sm[23];
    float p0x = xs - ptx, p0y = ys - pty, p0z = dv - ptz;
    float p1x = ip[0]*p0x + ip[1]*p0y + ip[2]*p0z;
    float p1y = ip[3]*p0x + ip[4]*p0y + ip[5]*p0z;
    float p1z = ip[6]*p0x + ip[7]*p0y + ip[8]*p0z;
    float qx = p1x * p1z, qy = p1y * p1z, qz = p1z;
    float rx = cmb[0]*qx + cmb[1]*qy + cmb[2]*qz + trx;
    float ry = cmb[3]*qx + cmb[4]*qy + cmb[5]*qz + trY;
    float rz = cmb[6]*qx + cmb[7]*qy + cmb[8]*qz + trz;
    const float lox = -50.8f - 0.4f;   // bx - dx/2, f32 fold matches np
    const float loy = -50.8f - 0.4f;
    const float loz = -10.0f;
    int ix = (int)((rx - lox) / 0.8f);   // trunc toward zero == astype(int32)
    int iy = (int)((ry - loy) / 0.8f);
    int iz = (int)((rz - loz) / 20.0f);
    // NZ == 1: valid iz is exactly 0
    bool val = (ix >= 0) && (ix < NX_) && (iy >= 0) && (iy < NY_) && (iz >= 0) && (iz < 1);
    return val ? (ix * NY_ + iy) : -1;
}

// One block per 1x4 pixel tile; all 6 cameras; cross-pixel voxel merge in LDS.
__global__ __launch_bounds__(512) void tile_kernel(
    const float* __restrict__ rots, const float* __restrict__ trans,
    const float* __restrict__ intrins, const float* __restrict__ post_rots,
    const float* __restrict__ post_trans,
    const float* __restrict__ img_feat, const float* __restrict__ depth_digit,
    float* __restrict__ outp)
{
    const int tb  = blockIdx.x;
    const int th  = tb / NTW_;
    const int w0  = (tb - th * NTW_) * TPX_;
    const int hw0 = th * WF_ + w0;
    const int tid  = threadIdx.x;
    const int lane = tid & 63;
    const int wave = tid >> 6;

    __shared__ float s_prob[PC_][D_];      // logits -> probs in place (10.75 KB)
    __shared__ short s_vox[PC_][D_];       // 5.25 KB
    __shared__ float s_wt[CAP_][WPAD_];    // 25.6 KB: per-slot weights for 24 lists
    __shared__ float s_featT[C_][PC_];     // 7.5 KB: feat[c][pc] (broadcast-friendly)
    __shared__ short s_slotvox[CAP_];      // slot -> global vox (-1 = dead)
    __shared__ float s_mat[N_][24];
    __shared__ float s_xs[TPX_];
    __shared__ int   s_bb[4];              // minx, maxx, miny, maxy
    __shared__ int   s_geo[5];             // ix0, iy0, bh, area, fb

    // ---- phase 1: stage inputs + zero accumulators ----
    for (int i = tid; i < PC_ * D_; i += 512) {
        int cd = i >> 2, px = i & 3;
        int cam = cd / D_, d = cd - cam * D_;
        s_prob[cam * TPX_ + px][d] = depth_digit[((size_t)cam * D_ + d) * HW_ + hw0 + px];
    }
    for (int i = tid; i < PC_ * C_; i += 512) {
        int cc = i >> 2, px = i & 3;
        int cam = cc / C_, c = cc - cam * C_;
        s_featT[c][cam * TPX_ + px] = img_feat[((size_t)cam * C_ + c) * HW_ + hw0 + px];
    }
    for (int i = tid; i < CAP_ * WPAD_; i += 512) ((float*)s_wt)[i] = 0.0f;
    for (int i = tid; i < CAP_; i += 512) s_slotvox[i] = -1;
    if (tid < 4) s_bb[tid] = (tid == 0 || tid == 2) ? INT_MAX : INT_MIN;
    if (tid >= 8 && tid < 12) s_xs[tid - 8] = (float)((double)(w0 + tid - 8) * (703.0 / 43.0));
    if (tid >= 16 && tid < 16 + N_) {
        int cam = tid - 16;
        float ipv[9], ii[9];
        inv3(post_rots + cam * 9, ipv);
        inv3(intrins + cam * 9, ii);
        const float* ro = rots + cam * 9;
        #pragma unroll
        for (int k = 0; k < 9; ++k) s_mat[cam][k] = ipv[k];
        #pragma unroll
        for (int r = 0; r < 3; ++r)
            #pragma unroll
            for (int c = 0; c < 3; ++c)
                s_mat[cam][9 + r * 3 + c] = ro[r*3+0]*ii[0*3+c] + ro[r*3+1]*ii[1*3+c] + ro[r*3+2]*ii[2*3+c];
        #pragma unroll
        for (int k = 0; k < 3; ++k) { s_mat[cam][18+k] = post_trans[cam*3+k]; s_mat[cam][21+k] = trans[cam*3+k]; }
    }
    __syncthreads();

    // ---- phase 2: softmax (3 lists per wave) + geometry + bbox ----
    #pragma unroll
    for (int j = 0; j < 3; ++j) {
        int pc = wave * 3 + j;
        bool act = lane < 56;
        float l0 = act ? s_prob[pc][lane]      : -INFINITY;
        float l1 = act ? s_prob[pc][lane + 56] : -INFINITY;
        float m = fmaxf(l0, l1);
        #pragma unroll
        for (int o = 32; o > 0; o >>= 1) m = fmaxf(m, __shfl_xor(m, o));
        float e0 = act ? __expf(l0 - m) : 0.0f;
        float e1 = act ? __expf(l1 - m) : 0.0f;
        float s = e0 + e1;
        #pragma unroll
        for (int o = 32; o > 0; o >>= 1) s += __shfl_xor(s, o);
        float inv = 1.0f / s;
        if (act) { s_prob[pc][lane] = e0 * inv; s_prob[pc][lane + 56] = e1 * inv; }
    }
    {
        float ys = (float)th * 17.0f;   // np.linspace(0,255,16)
        int mnx = INT_MAX, mxx = INT_MIN, mny = INT_MAX, mxy = INT_MIN;
        for (int i = tid; i < PC_ * D_; i += 512) {
            int pc = i / D_, d = i - pc * D_;
            int cam = pc >> 2, px = pc & 3;
            int v = voxel_of(s_xs[px], ys, 2.0f + 0.5f * (float)d, s_mat[cam]);
            s_vox[pc][d] = (short)v;
            if (v >= 0) {
                int ix = v >> 7, iy = v & 127;
                mnx = min(mnx, ix); mxx = max(mxx, ix);
                mny = min(mny, iy); mxy = max(mxy, iy);
            }
        }
        if (mxx >= 0) {
            atomicMin(&s_bb[0], mnx); atomicMax(&s_bb[1], mxx);
            atomicMin(&s_bb[2], mny); atomicMax(&s_bb[3], mxy);
        }
    }
    __syncthreads();

    if (tid == 0) {
        if (s_bb[1] < s_bb[0]) { s_geo[3] = 0; s_geo[4] = 0; }
        else {
            int bw = s_bb[1] - s_bb[0] + 1;
            int bh = s_bb[3] - s_bb[2] + 1;
            int area = bw * bh;
            s_geo[0] = s_bb[0]; s_geo[1] = s_bb[2]; s_geo[2] = bh;
            s_geo[3] = area; s_geo[4] = (area > CAP_) ? 1 : 0;
        }
    }
    __syncthreads();

    int area = s_geo[3];
    int fb   = s_geo[4];

    if (area > 0 && !fb) {
        // ---- phase 3: insert runs into bbox mini-plane (LDS atomics) ----
        int ix0 = s_geo[0], iy0 = s_geo[1], bh = s_geo[2];
        for (int i = tid; i < PC_ * D_; i += 512) {
            int pc = i / D_, d = i - pc * D_;
            int v = s_vox[pc][d];
            if (v >= 0) {
                int slot = ((v >> 7) - ix0) * bh + ((v & 127) - iy0);
                atomicAdd(&s_wt[slot][pc], s_prob[pc][d]);
                s_slotvox[slot] = (short)v;    // benign race, same value
            }
        }
        __syncthreads();

        // ---- phase 4: one global atomic per (live slot, channel) ----
        for (int k = tid; k < C_ * CAP_; k += 512) {
            int slot = k & (CAP_ - 1);
            int c    = k >> 8;
            if (slot < area) {
                int v = s_slotvox[slot];
                if (v >= 0) {
                    float val = 0.0f;
                    #pragma unroll
                    for (int j = 0; j < PC_; ++j)
                        val = fmaf(s_wt[slot][j], s_featT[c][j], val);
                    atomicAdd(&outp[(size_t)c * NPIX_ + v], val);
                }
            }
        }
    } else if (fb) {
        // ---- fallback (generic cameras, bbox too large): per-bin atomics ----
        for (int k = tid; k < PC_ * D_ * C_; k += 512) {
            int pcd = k / C_, c = k - pcd * C_;
            int pc = pcd / D_, d = pcd - pc * D_;
            int v = s_vox[pc][d];
            if (v >= 0)
                atomicAdd(&outp[(size_t)c * NPIX_ + v], s_prob[pc][d] * s_featT[c][pc]);
        }
    }
}

extern "C" void kernel_launch(void* const* d_in, const int* in_sizes, int n_in,
                              void* d_out, int out_size, void* d_ws, size_t ws_size,
                              hipStream_t stream) {
    const float* rots        = (const float*)d_in[1];
    const float* trans       = (const float*)d_in[2];
    const float* intrins     = (const float*)d_in[3];
    const float* post_rots   = (const float*)d_in[4];
    const float* post_trans  = (const float*)d_in[5];
    const float* img_feat    = (const float*)d_in[6];
    const float* depth_digit = (const float*)d_in[7];
    float* outp = (float*)d_out;

    (void)hipMemsetAsync(outp, 0, (size_t)out_size * sizeof(float), stream);
    tile_kernel<<<NT_, 512, 0, stream>>>(rots, trans, intrins, post_rots, post_trans,
                                         img_feat, depth_digit, outp);
}

// Round 10
// 96.672 us; speedup vs baseline: 1.6350x; 1.0524x over previous
//
#include <hip/hip_runtime.h>
#include <limits.h>

#define N_    6
#define C_    80
#define D_    112
#define HF_   16
#define WF_   44
#define NX_   128
#define NY_   128
#define HW_   (HF_ * WF_)          // 704
#define NPIX_ (NX_ * NY_)          // 16384
#define TPX_  4                    // pixels per tile (consecutive w)
#define NTW_  (WF_ / TPX_)         // 11
#define NT_   (HF_ * NTW_)         // 176 blocks
#define PC_   (N_ * TPX_)          // 24 (px,cam) lists per tile
#define CAP_  256                  // max bbox slots (fast path)
#define WPAD_ 25                   // s_wt row stride (coprime w/ 32 banks)
#define FPAD_ 25                   // s_featT row stride (coprime w/ 32 banks)

// ---------------- 3x3 inverse (adjugate) ----------------
__device__ __forceinline__ void inv3(const float* m, float* o) {
    float a = m[0], b = m[1], c = m[2];
    float d = m[3], e = m[4], f = m[5];
    float g = m[6], h = m[7], i = m[8];
    float A  =  (e * i - f * h);
    float Bc = -(d * i - f * g);
    float Cc =  (d * h - e * g);
    float det = a * A + b * Bc + c * Cc;
    float id = 1.0f / det;
    o[0] = A * id;                  o[1] = -(b * i - c * h) * id;   o[2] =  (b * f - c * e) * id;
    o[3] = Bc * id;                 o[4] =  (a * i - c * g) * id;   o[5] = -(a * f - c * d) * id;
    o[6] = Cc * id;                 o[7] = -(a * h - b * g) * id;   o[8] =  (a * e - b * d) * id;
}

__device__ __forceinline__ int voxel_of(float xs, float ys, float dv, const float* sm) {
    const float* ip  = sm;       // invPost
    const float* cmb = sm + 9;   // rots @ inv(intrins)
    float ptx = sm[18], pty = sm[19], ptz = sm[20];
    float trx = sm[21], trY = sm[22], trz = sm[23];
    float p0x = xs - ptx, p0y = ys - pty, p0z = dv - ptz;
    float p1x = ip[0]*p0x + ip[1]*p0y + ip[2]*p0z;
    float p1y = ip[3]*p0x + ip[4]*p0y + ip[5]*p0z;
    float p1z = ip[6]*p0x + ip[7]*p0y + ip[8]*p0z;
    float qx = p1x * p1z, qy = p1y * p1z, qz = p1z;
    float rx = cmb[0]*qx + cmb[1]*qy + cmb[2]*qz + trx;
    float ry = cmb[3]*qx + cmb[4]*qy + cmb[5]*qz + trY;
    float rz = cmb[6]*qx + cmb[7]*qy + cmb[8]*qz + trz;
    const float lox = -50.8f - 0.4f;   // bx - dx/2, f32 fold matches np
    const float loy = -50.8f - 0.4f;
    const float loz = -10.0f;
    int ix = (int)((rx - lox) / 0.8f);   // trunc toward zero == astype(int32)
    int iy = (int)((ry - loy) / 0.8f);
    int iz = (int)((rz - loz) / 20.0f);
    // NZ == 1: valid iz is exactly 0
    bool val = (ix >= 0) && (ix < NX_) && (iy >= 0) && (iy < NY_) && (iz >= 0) && (iz < 1);
    return val ? (ix * NY_ + iy) : -1;
}

// One block per 1x4 pixel tile; all 6 cameras; cross-pixel voxel merge in LDS.
__global__ __launch_bounds__(512) void tile_kernel(
    const float* __restrict__ rots, const float* __restrict__ trans,
    const float* __restrict__ intrins, const float* __restrict__ post_rots,
    const float* __restrict__ post_trans,
    const float* __restrict__ img_feat, const float* __restrict__ depth_digit,
    float* __restrict__ outp)
{
    const int tb  = blockIdx.x;
    const int th  = tb / NTW_;
    const int w0  = (tb - th * NTW_) * TPX_;
    const int hw0 = th * WF_ + w0;
    const int tid  = threadIdx.x;
    const int lane = tid & 63;
    const int wave = tid >> 6;

    __shared__ float s_prob[PC_][D_];      // logits -> probs in place (10.75 KB)
    __shared__ short s_vox[PC_][D_];       // 5.25 KB
    __shared__ float s_wt[CAP_][WPAD_];    // 25.6 KB: per-slot weights for 24 lists
    __shared__ float s_featT[C_][FPAD_];   // 8 KB: feat[c][pc], padded rows
    __shared__ short s_slotvox[CAP_];      // slot -> global vox (-1 = dead)
    __shared__ float s_mat[N_][24];
    __shared__ float s_xs[TPX_];
    __shared__ int   s_bb[4];              // minx, maxx, miny, maxy
    __shared__ int   s_geo[5];             // ix0, iy0, bh, area, fb

    // ---- phase 1: stage inputs + zero accumulators ----
    for (int i = tid; i < PC_ * D_; i += 512) {
        int cd = i >> 2, px = i & 3;
        int cam = cd / D_, d = cd - cam * D_;
        s_prob[cam * TPX_ + px][d] = depth_digit[((size_t)cam * D_ + d) * HW_ + hw0 + px];
    }
    for (int i = tid; i < PC_ * C_; i += 512) {
        int cc = i >> 2, px = i & 3;
        int cam = cc / C_, c = cc - cam * C_;
        s_featT[c][cam * TPX_ + px] = img_feat[((size_t)cam * C_ + c) * HW_ + hw0 + px];
    }
    for (int i = tid; i < CAP_ * WPAD_; i += 512) ((float*)s_wt)[i] = 0.0f;
    for (int i = tid; i < CAP_; i += 512) s_slotvox[i] = -1;
    if (tid < 4) s_bb[tid] = (tid == 0 || tid == 2) ? INT_MAX : INT_MIN;
    if (tid >= 8 && tid < 12) s_xs[tid - 8] = (float)((double)(w0 + tid - 8) * (703.0 / 43.0));
    if (tid >= 16 && tid < 16 + N_) {
        int cam = tid - 16;
        float ipv[9], ii[9];
        inv3(post_rots + cam * 9, ipv);
        inv3(intrins + cam * 9, ii);
        const float* ro = rots + cam * 9;
        #pragma unroll
        for (int k = 0; k < 9; ++k) s_mat[cam][k] = ipv[k];
        #pragma unroll
        for (int r = 0; r < 3; ++r)
            #pragma unroll
            for (int c = 0; c < 3; ++c)
                s_mat[cam][9 + r * 3 + c] = ro[r*3+0]*ii[0*3+c] + ro[r*3+1]*ii[1*3+c] + ro[r*3+2]*ii[2*3+c];
        #pragma unroll
        for (int k = 0; k < 3; ++k) { s_mat[cam][18+k] = post_trans[cam*3+k]; s_mat[cam][21+k] = trans[cam*3+k]; }
    }
    __syncthreads();

    // ---- phase 2: softmax (3 lists per wave) + geometry + bbox ----
    #pragma unroll
    for (int j = 0; j < 3; ++j) {
        int pc = wave * 3 + j;
        bool act = lane < 56;
        float l0 = act ? s_prob[pc][lane]      : -INFINITY;
        float l1 = act ? s_prob[pc][lane + 56] : -INFINITY;
        float m = fmaxf(l0, l1);
        #pragma unroll
        for (int o = 32; o > 0; o >>= 1) m = fmaxf(m, __shfl_xor(m, o));
        float e0 = act ? __expf(l0 - m) : 0.0f;
        float e1 = act ? __expf(l1 - m) : 0.0f;
        float s = e0 + e1;
        #pragma unroll
        for (int o = 32; o > 0; o >>= 1) s += __shfl_xor(s, o);
        float inv = 1.0f / s;
        if (act) { s_prob[pc][lane] = e0 * inv; s_prob[pc][lane + 56] = e1 * inv; }
    }
    {
        float ys = (float)th * 17.0f;   // np.linspace(0,255,16)
        int mnx = INT_MAX, mxx = INT_MIN, mny = INT_MAX, mxy = INT_MIN;
        for (int i = tid; i < PC_ * D_; i += 512) {
            int pc = i / D_, d = i - pc * D_;
            int cam = pc >> 2, px = pc & 3;
            int v = voxel_of(s_xs[px], ys, 2.0f + 0.5f * (float)d, s_mat[cam]);
            s_vox[pc][d] = (short)v;
            if (v >= 0) {
                int ix = v >> 7, iy = v & 127;
                mnx = min(mnx, ix); mxx = max(mxx, ix);
                mny = min(mny, iy); mxy = max(mxy, iy);
            }
        }
        if (mxx >= 0) {
            atomicMin(&s_bb[0], mnx); atomicMax(&s_bb[1], mxx);
            atomicMin(&s_bb[2], mny); atomicMax(&s_bb[3], mxy);
        }
    }
    __syncthreads();

    if (tid == 0) {
        if (s_bb[1] < s_bb[0]) { s_geo[3] = 0; s_geo[4] = 0; }
        else {
            int bw = s_bb[1] - s_bb[0] + 1;
            int bh = s_bb[3] - s_bb[2] + 1;
            int area = bw * bh;
            s_geo[0] = s_bb[0]; s_geo[1] = s_bb[2]; s_geo[2] = bh;
            s_geo[3] = area; s_geo[4] = (area > CAP_) ? 1 : 0;
        }
    }
    __syncthreads();

    int area = s_geo[3];
    int fb   = s_geo[4];

    if (area > 0 && !fb) {
        // ---- phase 3: insert runs into bbox mini-plane (LDS atomics) ----
        int ix0 = s_geo[0], iy0 = s_geo[1], bh = s_geo[2];
        for (int i = tid; i < PC_ * D_; i += 512) {
            int pc = i / D_, d = i - pc * D_;
            int v = s_vox[pc][d];
            if (v >= 0) {
                int slot = ((v >> 7) - ix0) * bh + ((v & 127) - iy0);
                atomicAdd(&s_wt[slot][pc], s_prob[pc][d]);
                s_slotvox[slot] = (short)v;    // benign race, same value
            }
        }
        __syncthreads();

        // ---- phase 4: one global atomic per (live slot, channel) ----
        int live = area * C_;
        for (int k = tid; k < live; k += 512) {
            int slot = k / C_;
            int c    = k - slot * C_;
            int v = s_slotvox[slot];
            if (v >= 0) {
                float val = 0.0f;
                #pragma unroll
                for (int j = 0; j < PC_; ++j)
                    val = fmaf(s_wt[slot][j], s_featT[c][j], val);
                atomicAdd(&outp[(size_t)c * NPIX_ + v], val);
            }
        }
    } else if (fb) {
        // ---- fallback (generic cameras, bbox too large): per-bin atomics ----
        for (int k = tid; k < PC_ * D_ * C_; k += 512) {
            int pcd = k / C_, c = k - pcd * C_;
            int pc = pcd / D_, d = pcd - pc * D_;
            int v = s_vox[pc][d];
            if (v >= 0)
                atomicAdd(&outp[(size_t)c * NPIX_ + v], s_prob[pc][d] * s_featT[c][pc]);
        }
    }
}

extern "C" void kernel_launch(void* const* d_in, const int* in_sizes, int n_in,
                              void* d_out, int out_size, void* d_ws, size_t ws_size,
                              hipStream_t stream) {
    const float* rots        = (const float*)d_in[1];
    const float* trans       = (const float*)d_in[2];
    const float* intrins     = (const float*)d_in[3];
    const float* post_rots   = (const float*)d_in[4];
    const float* post_trans  = (const float*)d_in[5];
    const float* img_feat    = (const float*)d_in[6];
    const float* depth_digit = (const float*)d_in[7];
    float* outp = (float*)d_out;

    (void)hipMemsetAsync(outp, 0, (size_t)out_size * sizeof(float), stream);
    tile_kernel<<<NT_, 512, 0, stream>>>(rots, trans, intrins, post_rots, post_trans,
                                         img_feat, depth_digit, outp);
}

// Round 11
// 96.054 us; speedup vs baseline: 1.6455x; 1.0064x over previous
//
#include <hip/hip_runtime.h>
#include <limits.h>

#define N_    6
#define C_    80
#define D_    112
#define HF_   16
#define WF_   44
#define NX_   128
#define NY_   128
#define HW_   (HF_ * WF_)          // 704
#define NPIX_ (NX_ * NY_)          // 16384
#define TPX_  4                    // pixels per tile (consecutive w)
#define NTW_  (WF_ / TPX_)         // 11
#define NT_   (HF_ * NTW_)         // 176 blocks
#define PC_   (N_ * TPX_)          // 24 (px,cam) lists per tile
#define CAP_  256                  // max bbox slots (fast path)
#define WPAD_ 25                   // s_wt row stride (coprime w/ 32 banks)
#define FPAD_ 25                   // s_featT row stride (coprime w/ 32 banks)

// ---------------- 3x3 inverse (adjugate) ----------------
__device__ __forceinline__ void inv3(const float* m, float* o) {
    float a = m[0], b = m[1], c = m[2];
    float d = m[3], e = m[4], f = m[5];
    float g = m[6], h = m[7], i = m[8];
    float A  =  (e * i - f * h);
    float Bc = -(d * i - f * g);
    float Cc =  (d * h - e * g);
    float det = a * A + b * Bc + c * Cc;
    float id = 1.0f / det;
    o[0] = A * id;                  o[1] = -(b * i - c * h) * id;   o[2] =  (b * f - c * e) * id;
    o[3] = Bc * id;                 o[4] =  (a * i - c * g) * id;   o[5] = -(a * f - c * d) * id;
    o[6] = Cc * id;                 o[7] = -(a * h - b * g) * id;   o[8] =  (a * e - b * d) * id;
}

__device__ __forceinline__ int voxel_of(float xs, float ys, float dv, const float* sm) {
    const float* ip  = sm;       // invPost
    const float* cmb = sm + 9;   // rots @ inv(intrins)
    float ptx = sm[18], pty = sm[19], ptz = sm[20];
    float trx = sm[21], trY = sm[22], trz = sm[23];
    float p0x = xs - ptx, p0y = ys - pty, p0z = dv - ptz;
    float p1x = ip[0]*p0x + ip[1]*p0y + ip[2]*p0z;
    float p1y = ip[3]*p0x + ip[4]*p0y + ip[5]*p0z;
    float p1z = ip[6]*p0x + ip[7]*p0y + ip[8]*p0z;
    float qx = p1x * p1z, qy = p1y * p1z, qz = p1z;
    float rx = cmb[0]*qx + cmb[1]*qy + cmb[2]*qz + trx;
    float ry = cmb[3]*qx + cmb[4]*qy + cmb[5]*qz + trY;
    float rz = cmb[6]*qx + cmb[7]*qy + cmb[8]*qz + trz;
    const float lox = -50.8f - 0.4f;   // bx - dx/2, f32 fold matches np
    const float loy = -50.8f - 0.4f;
    const float loz = -10.0f;
    int ix = (int)((rx - lox) / 0.8f);   // trunc toward zero == astype(int32)
    int iy = (int)((ry - loy) / 0.8f);
    int iz = (int)((rz - loz) / 20.0f);
    // NZ == 1: valid iz is exactly 0
    bool val = (ix >= 0) && (ix < NX_) && (iy >= 0) && (iy < NY_) && (iz >= 0) && (iz < 1);
    return val ? (ix * NY_ + iy) : -1;
}

// One block per 1x4 pixel tile; all 6 cameras; cross-pixel voxel merge in LDS.
__global__ __launch_bounds__(512) void tile_kernel(
    const float* __restrict__ rots, const float* __restrict__ trans,
    const float* __restrict__ intrins, const float* __restrict__ post_rots,
    const float* __restrict__ post_trans,
    const float* __restrict__ img_feat, const float* __restrict__ depth_digit,
    float* __restrict__ outp)
{
    const int tb  = blockIdx.x;
    const int th  = tb / NTW_;
    const int w0  = (tb - th * NTW_) * TPX_;
    const int hw0 = th * WF_ + w0;     // % 4 == 0 -> float4-aligned rows
    const int tid  = threadIdx.x;
    const int lane = tid & 63;
    const int wave = tid >> 6;

    __shared__ float s_prob[PC_][D_];      // logits -> probs in place (10.75 KB)
    __shared__ short s_vox[PC_][D_];       // 5.25 KB
    __shared__ float s_wt[CAP_][WPAD_];    // 25.6 KB: per-slot weights for 24 lists
    __shared__ float s_featT[C_][FPAD_];   // 8 KB: feat[c][pc], padded rows
    __shared__ short s_slotvox[CAP_];      // slot -> global vox (-1 = dead)
    __shared__ float s_mat[N_][24];
    __shared__ float s_xs[TPX_];
    __shared__ int   s_bb[4];              // minx, maxx, miny, maxy
    __shared__ int   s_geo[5];             // ix0, iy0, bh, area, fb

    // ---- phase 1: stage inputs (float4 per (cam,row)) + zero accumulators ----
    for (int i = tid; i < N_ * D_; i += 512) {
        int cam = i / D_, d = i - cam * D_;
        float4 v = *(const float4*)(depth_digit + ((size_t)cam * D_ + d) * HW_ + hw0);
        int pc0 = cam * TPX_;
        s_prob[pc0 + 0][d] = v.x;
        s_prob[pc0 + 1][d] = v.y;
        s_prob[pc0 + 2][d] = v.z;
        s_prob[pc0 + 3][d] = v.w;
    }
    for (int i = tid; i < N_ * C_; i += 512) {
        int cam = i / C_, c = i - cam * C_;
        float4 v = *(const float4*)(img_feat + ((size_t)cam * C_ + c) * HW_ + hw0);
        int pc0 = cam * TPX_;
        s_featT[c][pc0 + 0] = v.x;
        s_featT[c][pc0 + 1] = v.y;
        s_featT[c][pc0 + 2] = v.z;
        s_featT[c][pc0 + 3] = v.w;
    }
    for (int i = tid; i < CAP_ * WPAD_; i += 512) ((float*)s_wt)[i] = 0.0f;
    for (int i = tid; i < CAP_; i += 512) s_slotvox[i] = -1;
    if (tid < 4) s_bb[tid] = (tid == 0 || tid == 2) ? INT_MAX : INT_MIN;
    if (tid >= 8 && tid < 12) s_xs[tid - 8] = (float)((double)(w0 + tid - 8) * (703.0 / 43.0));
    if (tid >= 16 && tid < 16 + N_) {
        int cam = tid - 16;
        float ipv[9], ii[9];
        inv3(post_rots + cam * 9, ipv);
        inv3(intrins + cam * 9, ii);
        const float* ro = rots + cam * 9;
        #pragma unroll
        for (int k = 0; k < 9; ++k) s_mat[cam][k] = ipv[k];
        #pragma unroll
        for (int r = 0; r < 3; ++r)
            #pragma unroll
            for (int c = 0; c < 3; ++c)
                s_mat[cam][9 + r * 3 + c] = ro[r*3+0]*ii[0*3+c] + ro[r*3+1]*ii[1*3+c] + ro[r*3+2]*ii[2*3+c];
        #pragma unroll
        for (int k = 0; k < 3; ++k) { s_mat[cam][18+k] = post_trans[cam*3+k]; s_mat[cam][21+k] = trans[cam*3+k]; }
    }
    __syncthreads();

    // ---- phase 2: softmax (3 lists per wave) + geometry + bbox ----
    #pragma unroll
    for (int j = 0; j < 3; ++j) {
        int pc = wave * 3 + j;
        bool act = lane < 56;
        float l0 = act ? s_prob[pc][lane]      : -INFINITY;
        float l1 = act ? s_prob[pc][lane + 56] : -INFINITY;
        float m = fmaxf(l0, l1);
        #pragma unroll
        for (int o = 32; o > 0; o >>= 1) m = fmaxf(m, __shfl_xor(m, o));
        float e0 = act ? __expf(l0 - m) : 0.0f;
        float e1 = act ? __expf(l1 - m) : 0.0f;
        float s = e0 + e1;
        #pragma unroll
        for (int o = 32; o > 0; o >>= 1) s += __shfl_xor(s, o);
        float inv = 1.0f / s;
        if (act) { s_prob[pc][lane] = e0 * inv; s_prob[pc][lane + 56] = e1 * inv; }
    }
    {
        float ys = (float)th * 17.0f;   // np.linspace(0,255,16)
        int mnx = INT_MAX, mxx = INT_MIN, mny = INT_MAX, mxy = INT_MIN;
        for (int i = tid; i < PC_ * D_; i += 512) {
            int pc = i / D_, d = i - pc * D_;
            int cam = pc >> 2, px = pc & 3;
            int v = voxel_of(s_xs[px], ys, 2.0f + 0.5f * (float)d, s_mat[cam]);
            s_vox[pc][d] = (short)v;
            if (v >= 0) {
                int ix = v >> 7, iy = v & 127;
                mnx = min(mnx, ix); mxx = max(mxx, ix);
                mny = min(mny, iy); mxy = max(mxy, iy);
            }
        }
        if (mxx >= 0) {
            atomicMin(&s_bb[0], mnx); atomicMax(&s_bb[1], mxx);
            atomicMin(&s_bb[2], mny); atomicMax(&s_bb[3], mxy);
        }
    }
    __syncthreads();

    if (tid == 0) {
        if (s_bb[1] < s_bb[0]) { s_geo[3] = 0; s_geo[4] = 0; }
        else {
            int bw = s_bb[1] - s_bb[0] + 1;
            int bh = s_bb[3] - s_bb[2] + 1;
            int area = bw * bh;
            s_geo[0] = s_bb[0]; s_geo[1] = s_bb[2]; s_geo[2] = bh;
            s_geo[3] = area; s_geo[4] = (area > CAP_) ? 1 : 0;
        }
    }
    __syncthreads();

    int area = s_geo[3];
    int fb   = s_geo[4];

    if (area > 0 && !fb) {
        // ---- phase 3: insert runs into bbox mini-plane (LDS atomics) ----
        int ix0 = s_geo[0], iy0 = s_geo[1], bh = s_geo[2];
        for (int i = tid; i < PC_ * D_; i += 512) {
            int pc = i / D_, d = i - pc * D_;
            int v = s_vox[pc][d];
            if (v >= 0) {
                int slot = ((v >> 7) - ix0) * bh + ((v & 127) - iy0);
                atomicAdd(&s_wt[slot][pc], s_prob[pc][d]);
                s_slotvox[slot] = (short)v;    // benign race, same value
            }
        }
        __syncthreads();

        // ---- phase 4: one global atomic per (live slot, channel) ----
        int live = area * C_;
        for (int k = tid; k < live; k += 512) {
            int slot = k / C_;
            int c    = k - slot * C_;
            int v = s_slotvox[slot];
            if (v >= 0) {
                float val = 0.0f;
                #pragma unroll
                for (int j = 0; j < PC_; ++j)
                    val = fmaf(s_wt[slot][j], s_featT[c][j], val);
                atomicAdd(&outp[(size_t)c * NPIX_ + v], val);
            }
        }
    } else if (fb) {
        // ---- fallback (generic cameras, bbox too large): per-bin atomics ----
        for (int k = tid; k < PC_ * D_ * C_; k += 512) {
            int pcd = k / C_, c = k - pcd * C_;
            int pc = pcd / D_, d = pcd - pc * D_;
            int v = s_vox[pc][d];
            if (v >= 0)
                atomicAdd(&outp[(size_t)c * NPIX_ + v], s_prob[pc][d] * s_featT[c][pc]);
        }
    }
}

extern "C" void kernel_launch(void* const* d_in, const int* in_sizes, int n_in,
                              void* d_out, int out_size, void* d_ws, size_t ws_size,
                              hipStream_t stream) {
    const float* rots        = (const float*)d_in[1];
    const float* trans       = (const float*)d_in[2];
    const float* intrins     = (const float*)d_in[3];
    const float* post_rots   = (const float*)d_in[4];
    const float* post_trans  = (const float*)d_in[5];
    const float* img_feat    = (const float*)d_in[6];
    const float* depth_digit = (const float*)d_in[7];
    float* outp = (float*)d_out;

    (void)hipMemsetAsync(outp, 0, (size_t)out_size * sizeof(float), stream);
    tile_kernel<<<NT_, 512, 0, stream>>>(rots, trans, intrins, post_rots, post_trans,
                                         img_feat, depth_digit, outp);
}